// Round 14
// baseline (219.557 us; speedup 1.0000x reference)
//
#include <hip/hip_runtime.h>
#include <hip/hip_bf16.h>
#include <cstdint>
#include <cstddef>

#define LAYERS 3
#define EMB 256
#define NB 4096
#define MAXLEN 50
#define NITEMS 50000
#define SPLITK 2

typedef float f32x4 __attribute__((ext_vector_type(4)));
typedef __bf16 bf16x8 __attribute__((ext_vector_type(8)));
typedef unsigned short u16;

static __device__ __forceinline__ u16 f2bf(float f) {
  union { float f; uint32_t u; } v; v.f = f;
  uint32_t r = v.u + 0x7FFFu + ((v.u >> 16) & 1u);
  return (u16)(r >> 16);
}

static __device__ __forceinline__ float bf2f(u16 h) {
  union { uint32_t u; float f; } v; v.u = (uint32_t)h << 16; return v.f;
}

static __device__ __forceinline__ f32x4 bfu4(ushort4 h) {
  f32x4 r; r.x = bf2f(h.x); r.y = bf2f(h.y); r.z = bf2f(h.z); r.w = bf2f(h.w);
  return r;
}

static __device__ __forceinline__ ushort4 f2bf4(f32x4 v) {
  ushort4 o; o.x = f2bf(v.x); o.y = f2bf(v.y); o.z = f2bf(v.z); o.w = f2bf(v.w);
  return o;
}

#define N4_D (NB * NB / 4)
#define N4_W (LAYERS * EMB * EMB / 4)
#define N4_E ((NITEMS + 1) * EMB / 4)

// ---- single grid-stride pack: D, A, w -> bf16; emb -> padded bf16 table (r8-proven) ----
__global__ void pack_all(const float* __restrict__ D, const float* __restrict__ A,
                         const float* __restrict__ w, const float* __restrict__ emb,
                         u16* __restrict__ Db, u16* __restrict__ Ab,
                         u16* __restrict__ wb, u16* __restrict__ ebp) {
  const int total = N4_D + N4_D + N4_W + N4_E;
  for (int i = blockIdx.x * blockDim.x + threadIdx.x; i < total;
       i += gridDim.x * blockDim.x) {
    int j = i;
    if (j < N4_D) {
      reinterpret_cast<ushort4*>(Db)[j] = f2bf4(reinterpret_cast<const f32x4*>(D)[j]);
    } else if ((j -= N4_D) < N4_D) {
      reinterpret_cast<ushort4*>(Ab)[j] = f2bf4(reinterpret_cast<const f32x4*>(A)[j]);
    } else if ((j -= N4_D) < N4_W) {
      reinterpret_cast<ushort4*>(wb)[j] = f2bf4(reinterpret_cast<const f32x4*>(w)[j]);
    } else {
      j -= N4_W;
      ushort4 o = {0, 0, 0, 0};
      if (j >= EMB / 4) o = f2bf4(reinterpret_cast<const f32x4*>(emb)[j - EMB / 4]);
      reinterpret_cast<ushort4*>(ebp)[j] = o;
    }
  }
}

// ---- gather + mean pool (1 wave/session, bf16 padded table, 5-deep MLP; r8-proven) ----
__global__ void gather_mean(const u16* __restrict__ ebp, const int* __restrict__ items,
                            const float* __restrict__ slen, float* __restrict__ acc,
                            u16* __restrict__ xb) {
  int w = threadIdx.x >> 6, lane = threadIdx.x & 63;
  int b = blockIdx.x * 4 + w;
  f32x4 s = {0.f, 0.f, 0.f, 0.f};
  const int* it = items + (size_t)b * MAXLEN;
  const int le = lane * 4;
#pragma unroll 2
  for (int l = 0; l < MAXLEN; l += 5) {
    int i0 = it[l], i1 = it[l + 1], i2 = it[l + 2], i3 = it[l + 3], i4 = it[l + 4];
    ushort4 v0 = *reinterpret_cast<const ushort4*>(ebp + (size_t)i0 * EMB + le);
    ushort4 v1 = *reinterpret_cast<const ushort4*>(ebp + (size_t)i1 * EMB + le);
    ushort4 v2 = *reinterpret_cast<const ushort4*>(ebp + (size_t)i2 * EMB + le);
    ushort4 v3 = *reinterpret_cast<const ushort4*>(ebp + (size_t)i3 * EMB + le);
    ushort4 v4 = *reinterpret_cast<const ushort4*>(ebp + (size_t)i4 * EMB + le);
    s += bfu4(v0) + bfu4(v1) + bfu4(v2) + bfu4(v3) + bfu4(v4);
  }
  float inv = 1.0f / slen[b];
  s *= inv;
  *reinterpret_cast<f32x4*>(acc + (size_t)b * EMB + le) = s;
  *reinterpret_cast<ushort4*>(xb + (size_t)b * EMB + le) = f2bf4(s);
}

// ---- wave-split-K GEMM 64x64: 4 waves, each owns a K-slice + private 16KB LDS region ----
// C[M][N] = sum_k Am[m][k]*Bt[n][k]. No barriers in K-loop (per-wave vmcnt/lgkmcnt);
// in-block reduction of the 4 wave accumulators through LDS. Swizzle identical to r13.
__global__ __launch_bounds__(256) void gemm_ws(const u16* __restrict__ Am,
                                               const u16* __restrict__ Bt,
                                               u16* __restrict__ C,
                                               int M, int N, int K, size_t zstride) {
  __shared__ __align__(16) u16 S[4][8192];  // per-wave: As 4096 u16 + Bs 4096 u16
  const int tid = threadIdx.x;
  const int lane = tid & 63;
  const int wid = tid >> 6;
  u16* As = S[wid];
  u16* Bs = S[wid] + 4096;
  const int row0 = blockIdx.y * 64, col0 = blockIdx.x * 64;
  const int kslice = K / (int)(gridDim.z * 4);
  const int kb = ((int)blockIdx.z * 4 + wid) * kslice;
  C += (size_t)blockIdx.z * zstride;

  f32x4 acc[4][4];
#pragma unroll
  for (int m = 0; m < 4; m++)
#pragma unroll
    for (int n = 0; n < 4; n++)
#pragma unroll
      for (int j = 0; j < 4; j++) acc[m][n][j] = 0.0f;

  const int lrow = lane & 15;
  const int lhi = lane >> 4;
  const int sw7 = lane & 7;                         // == frag row & 7
  const int lr8 = lane >> 3;                        // staging row within 8-row group
  const int cswz = ((lane & 7) ^ lr8) * 8;          // inverse-swizzled source k-offset

  for (int k0 = kb; k0 < kb + kslice; k0 += 64) {
    // drain this wave's ds_reads before overwriting its region (per-wave, cheap)
    asm volatile("s_waitcnt lgkmcnt(0)" ::: "memory");
#pragma unroll
    for (int i = 0; i < 8; i++) {
      int row = i * 8 + lr8;
      __builtin_amdgcn_global_load_lds(
          (const __attribute__((address_space(1))) void*)(Am + (size_t)(row0 + row) * K + k0 + cswz),
          (__attribute__((address_space(3))) void*)(As + (size_t)(i * 64 + lane) * 8), 16, 0, 0);
    }
#pragma unroll
    for (int i = 0; i < 8; i++) {
      int row = i * 8 + lr8;
      __builtin_amdgcn_global_load_lds(
          (const __attribute__((address_space(1))) void*)(Bt + (size_t)(col0 + row) * K + k0 + cswz),
          (__attribute__((address_space(3))) void*)(Bs + (size_t)(i * 64 + lane) * 8), 16, 0, 0);
    }
    asm volatile("s_waitcnt vmcnt(0)" ::: "memory");  // per-wave: own loads only

#pragma unroll
    for (int kk = 0; kk < 2; kk++) {
      const int co = ((kk * 4 + lhi) ^ sw7) * 8;
      bf16x8 af[4], bfv[4];
#pragma unroll
      for (int m = 0; m < 4; m++)
        af[m] = *reinterpret_cast<const bf16x8*>(As + (size_t)(m * 16 + lrow) * 64 + co);
#pragma unroll
      for (int n = 0; n < 4; n++)
        bfv[n] = *reinterpret_cast<const bf16x8*>(Bs + (size_t)(n * 16 + lrow) * 64 + co);
#pragma unroll
      for (int m = 0; m < 4; m++)
#pragma unroll
        for (int n = 0; n < 4; n++)
          acc[m][n] = __builtin_amdgcn_mfma_f32_16x16x32_bf16(af[m], bfv[n], acc[m][n], 0, 0, 0);
    }
  }

  // dump this wave's 64x64 f32 acc into its own region (exactly 16 KB)
  float* dump = reinterpret_cast<float*>(S[wid]);
#pragma unroll
  for (int m = 0; m < 4; m++)
#pragma unroll
    for (int n = 0; n < 4; n++)
#pragma unroll
      for (int j = 0; j < 4; j++)
        dump[(m * 16 + lhi * 4 + j) * 64 + n * 16 + lrow] = acc[m][n][j];
  __syncthreads();

  // 256 threads sum the 4 copies; thread t owns 16 consecutive elems
  const int r = tid >> 2, cb = (tid & 3) * 16;
  f32x4 s0 = {0, 0, 0, 0}, s1 = s0, s2 = s0, s3 = s0;
#pragma unroll
  for (int w = 0; w < 4; w++) {
    const float* src = reinterpret_cast<const float*>(S[w]) + r * 64 + cb;
    s0 += *reinterpret_cast<const f32x4*>(src);
    s1 += *reinterpret_cast<const f32x4*>(src + 4);
    s2 += *reinterpret_cast<const f32x4*>(src + 8);
    s3 += *reinterpret_cast<const f32x4*>(src + 12);
  }
  u16* cp = C + (size_t)(row0 + r) * N + col0 + cb;
  *reinterpret_cast<ushort4*>(cp) = f2bf4(s0);
  *reinterpret_cast<ushort4*>(cp + 4) = f2bf4(s1);
  *reinterpret_cast<ushort4*>(cp + 8) = f2bf4(s2);
  *reinterpret_cast<ushort4*>(cp + 12) = f2bf4(s3);
}

// ---- GEMM 64x64, K=256 staged in ONE shot (single barrier): yT = W x^T (r9-13 proven) ----
__global__ __launch_bounds__(256) void gemm64_ss(const u16* __restrict__ Am,
                                                 const u16* __restrict__ Bt,
                                                 u16* __restrict__ C, int N) {
  __shared__ __align__(16) u16 As[64 * 256];
  __shared__ __align__(16) u16 Bs[64 * 256];
  const int tid = threadIdx.x;
  const int lane = tid & 63;
  const int wid = tid >> 6;
  const int wr = wid >> 1, wc = wid & 1;
  const int row0 = blockIdx.y * 64, col0 = blockIdx.x * 64;
  const int lrow = lane & 15;
  const int lhi = lane >> 4;
  const int sw7 = lane & 7;

#pragma unroll
  for (int i = 0; i < 8; i++) {
    int row = i * 8 + (tid >> 5);
    int sc = (tid & 31) ^ (row & 7);
    __builtin_amdgcn_global_load_lds(
        (const __attribute__((address_space(1))) void*)(Am + (size_t)(row0 + row) * EMB + sc * 8),
        (__attribute__((address_space(3))) void*)((char*)As + (i * 256 + wid * 64) * 16), 16, 0, 0);
    __builtin_amdgcn_global_load_lds(
        (const __attribute__((address_space(1))) void*)(Bt + (size_t)(col0 + row) * EMB + sc * 8),
        (__attribute__((address_space(3))) void*)((char*)Bs + (i * 256 + wid * 64) * 16), 16, 0, 0);
  }
  __syncthreads();

  f32x4 acc[2][2];
#pragma unroll
  for (int m = 0; m < 2; m++)
#pragma unroll
    for (int n = 0; n < 2; n++)
#pragma unroll
      for (int j = 0; j < 4; j++) acc[m][n][j] = 0.0f;

#pragma unroll
  for (int ks = 0; ks < 8; ks++) {
    const int co = ((ks * 4 + lhi) ^ sw7) * 8;
    bf16x8 af[2], bfv[2];
#pragma unroll
    for (int m = 0; m < 2; m++)
      af[m] = *reinterpret_cast<const bf16x8*>(As + (size_t)(wr * 32 + m * 16 + lrow) * 256 + co);
#pragma unroll
    for (int n = 0; n < 2; n++)
      bfv[n] = *reinterpret_cast<const bf16x8*>(Bs + (size_t)(wc * 32 + n * 16 + lrow) * 256 + co);
#pragma unroll
    for (int m = 0; m < 2; m++)
#pragma unroll
      for (int n = 0; n < 2; n++)
        acc[m][n] = __builtin_amdgcn_mfma_f32_16x16x32_bf16(af[m], bfv[n], acc[m][n], 0, 0, 0);
  }

#pragma unroll
  for (int m = 0; m < 2; m++) {
#pragma unroll
    for (int j = 0; j < 4; j++) {
      int r = row0 + wr * 32 + m * 16 + lhi * 4 + j;
      u16* cp = C + (size_t)r * N + col0 + wc * 32 + lrow;
#pragma unroll
      for (int n = 0; n < 2; n++) cp[n * 16] = f2bf(acc[m][n][j]);
    }
  }
}

// ---- sum bf16 split-K partials -> bf16 (for uT); SPLITK unrolled ----
__global__ void uredux(const u16* __restrict__ zp, u16* __restrict__ uT,
                       int n4, size_t zstride4) {
  int i = blockIdx.x * blockDim.x + threadIdx.x;
  if (i < n4) {
    ushort4 v[SPLITK];
#pragma unroll
    for (int k = 0; k < SPLITK; k++)
      v[k] = reinterpret_cast<const ushort4*>(zp)[(size_t)k * zstride4 + i];
    f32x4 s = {0.f, 0.f, 0.f, 0.f};
#pragma unroll
    for (int k = 0; k < SPLITK; k++) s += bfu4(v[k]);
    reinterpret_cast<ushort4*>(uT)[i] = f2bf4(s);
  }
}

// ---- bf16 split-K reduce + row norm + accumulate (+final scale); SPLITK unrolled ----
__global__ void norm_acc(const u16* __restrict__ zp, size_t zstride,
                         float* __restrict__ acc, u16* __restrict__ xb,
                         float* __restrict__ outp, int fin) {
  int b = blockIdx.x, t = threadIdx.x;
  size_t i = (size_t)b * EMB + t;
  u16 h[SPLITK];
#pragma unroll
  for (int s = 0; s < SPLITK; s++) h[s] = zp[(size_t)s * zstride + i];
  float v = 0.0f;
#pragma unroll
  for (int s = 0; s < SPLITK; s++) v += bf2f(h[s]);
  float s2 = v * v;
#pragma unroll
  for (int o = 32; o > 0; o >>= 1) s2 += __shfl_down(s2, o, 64);
  __shared__ float ws4[4];
  if ((t & 63) == 0) ws4[t >> 6] = s2;
  __syncthreads();
  float tot = ws4[0] + ws4[1] + ws4[2] + ws4[3];
  float rn = 1.0f / fmaxf(sqrtf(tot), 1e-12f);
  if (fin) {
    outp[i] = (acc[i] + v * rn) * 0.25f;
  } else {
    acc[i] += v * rn;
    xb[i] = f2bf(v);
  }
}

// ---- launch ----
// Per layer: yT = Wx^T (gemm64_ss) ; uT = (A@y)^T (gemm_ws, grid-splitK=2 x in-block
// wave-splitK=4 -> uredux) ; z = D@u (gemm_ws -> norm_acc). Partial traffic 32->8 MB/chain.
extern "C" void kernel_launch(void* const* d_in, const int* in_sizes, int n_in,
                              void* d_out, int out_size, void* d_ws, size_t ws_size,
                              hipStream_t stream) {
  const float* emb   = (const float*)d_in[0];
  const float* D     = (const float*)d_in[1];
  const float* A     = (const float*)d_in[2];
  const int*   items = (const int*)d_in[3];
  const float* slen  = (const float*)d_in[4];
  const float* w     = (const float*)d_in[5];
  float* out = (float*)d_out;

  // workspace carve (~100 MB); zp (4 MB) overlays ebp (dead after gather_mean)
  char* p = (char*)d_ws;
  u16* Db   = (u16*)p;   p += (size_t)NB * NB * 2;             // 32 MB
  u16* Ab   = (u16*)p;   p += (size_t)NB * NB * 2;             // 32 MB
  float* accf = (float*)p; p += (size_t)NB * EMB * 4;          // 4 MB
  u16* xb   = (u16*)p;   p += (size_t)NB * EMB * 2;            // 2 MB
  u16* yT   = (u16*)p;   p += (size_t)EMB * NB * 2;            // 2 MB
  u16* uT   = (u16*)p;   p += (size_t)EMB * NB * 2;            // 2 MB
  u16* wb   = (u16*)p;   p += (size_t)LAYERS * EMB * EMB * 2;  // 0.4 MB
  u16* ebp  = (u16*)p;   p += (size_t)(NITEMS + 1) * EMB * 2;  // 25.6 MB
  u16* zp   = ebp;  // SPLITK x [NB][EMB] bf16 = 4 MB in dead ebp region

  pack_all<<<2048, 256, 0, stream>>>(D, A, w, emb, Db, Ab, wb, ebp);
  gather_mean<<<NB / 4, 256, 0, stream>>>(ebp, items, slen, accf, xb);

  for (int i = 0; i < LAYERS; i++) {
    // yT[e][b] = sum_f W[e][f] * x[b][f]
    gemm64_ss<<<dim3(NB / 64, EMB / 64), 256, 0, stream>>>(wb + (size_t)i * EMB * EMB, xb, yT,
                                                           NB);
    // uT partials: zp[s][e][b] = partial_j yT[e][j] * Ab[b][j]  (M=256, N=4096)
    gemm_ws<<<dim3(NB / 64, EMB / 64, SPLITK), 256, 0, stream>>>(
        yT, Ab, zp, EMB, NB, NB, (size_t)EMB * NB);
    uredux<<<EMB * NB / 4 / 256, 256, 0, stream>>>(zp, uT, EMB * NB / 4,
                                                   (size_t)EMB * NB / 4);
    // z partials: zp[s][b][e] = partial_j Db[b][j] * uT[e][j]   (M=4096, N=256)
    gemm_ws<<<dim3(EMB / 64, NB / 64, SPLITK), 256, 0, stream>>>(
        Db, uT, zp, NB, EMB, NB, (size_t)NB * EMB);
    norm_acc<<<NB, 256, 0, stream>>>(zp, (size_t)NB * EMB, accf, xb, out, i == LAYERS - 1);
  }
}

// Round 15
// 204.899 us; speedup vs baseline: 1.0715x; 1.0715x over previous
//
#include <hip/hip_runtime.h>
#include <hip/hip_bf16.h>
#include <cstdint>
#include <cstddef>

#define LAYERS 3
#define EMB 256
#define NB 4096
#define MAXLEN 50
#define NITEMS 50000
#define SPLITK 8
#define PACK_BLOCKS 2048

typedef float f32x4 __attribute__((ext_vector_type(4)));
typedef __bf16 bf16x8 __attribute__((ext_vector_type(8)));
typedef unsigned short u16;

static __device__ __forceinline__ u16 f2bf(float f) {
  union { float f; uint32_t u; } v; v.f = f;
  uint32_t r = v.u + 0x7FFFu + ((v.u >> 16) & 1u);
  return (u16)(r >> 16);
}

static __device__ __forceinline__ float bf2f(u16 h) {
  union { uint32_t u; float f; } v; v.u = (uint32_t)h << 16; return v.f;
}

static __device__ __forceinline__ f32x4 bfu4(ushort4 h) {
  f32x4 r; r.x = bf2f(h.x); r.y = bf2f(h.y); r.z = bf2f(h.z); r.w = bf2f(h.w);
  return r;
}

static __device__ __forceinline__ ushort4 f2bf4(f32x4 v) {
  ushort4 o; o.x = f2bf(v.x); o.y = f2bf(v.y); o.z = f2bf(v.z); o.w = f2bf(v.w);
  return o;
}

template <typename T> __device__ __forceinline__ T cvt_out(float v);
template <> __device__ __forceinline__ float cvt_out<float>(float v) { return v; }
template <> __device__ __forceinline__ u16 cvt_out<u16>(float v) { return f2bf(v); }

#define N4_D (NB * NB / 4)
#define N4_W (LAYERS * EMB * EMB / 4)

// ---- block-specialized: blocks [0,PACK_BLOCKS) pack D/A/w -> bf16;
//      blocks [PACK_BLOCKS, PACK_BLOCKS+NB/4) gather+mean-pool from the f32 table.
//      The two roles are independent (gather reads raw f32 emb) -> they co-execute,
//      hiding gather's latency under pack's and removing the 77 MB ebp round-trip.
__global__ void pack_gather(const float* __restrict__ D, const float* __restrict__ A,
                            const float* __restrict__ w, const float* __restrict__ emb,
                            const int* __restrict__ items, const float* __restrict__ slen,
                            u16* __restrict__ Db, u16* __restrict__ Ab,
                            u16* __restrict__ wb, float* __restrict__ accf,
                            u16* __restrict__ xb) {
  if (blockIdx.x < PACK_BLOCKS) {
    const int total = N4_D + N4_D + N4_W;
    for (int i = blockIdx.x * blockDim.x + threadIdx.x; i < total;
         i += PACK_BLOCKS * blockDim.x) {
      int j = i;
      if (j < N4_D) {
        reinterpret_cast<ushort4*>(Db)[j] = f2bf4(reinterpret_cast<const f32x4*>(D)[j]);
      } else if ((j -= N4_D) < N4_D) {
        reinterpret_cast<ushort4*>(Ab)[j] = f2bf4(reinterpret_cast<const f32x4*>(A)[j]);
      } else {
        j -= N4_D;
        reinterpret_cast<ushort4*>(wb)[j] = f2bf4(reinterpret_cast<const f32x4*>(w)[j]);
      }
    }
  } else {
    // gather (r11-proven): clamped address + 0/1 multiplier, 5 loads in flight
    int g = blockIdx.x - PACK_BLOCKS;
    int wv = threadIdx.x >> 6, lane = threadIdx.x & 63;
    int b = g * 4 + wv;
    f32x4 s = {0.f, 0.f, 0.f, 0.f};
    const int* it = items + (size_t)b * MAXLEN;
    const int le = lane * 4;
#pragma unroll 2
    for (int l = 0; l < MAXLEN; l += 5) {
      int i0 = it[l], i1 = it[l + 1], i2 = it[l + 2], i3 = it[l + 3], i4 = it[l + 4];
      f32x4 v0 = *reinterpret_cast<const f32x4*>(emb + (size_t)(i0 > 0 ? i0 - 1 : 0) * EMB + le);
      f32x4 v1 = *reinterpret_cast<const f32x4*>(emb + (size_t)(i1 > 0 ? i1 - 1 : 0) * EMB + le);
      f32x4 v2 = *reinterpret_cast<const f32x4*>(emb + (size_t)(i2 > 0 ? i2 - 1 : 0) * EMB + le);
      f32x4 v3 = *reinterpret_cast<const f32x4*>(emb + (size_t)(i3 > 0 ? i3 - 1 : 0) * EMB + le);
      f32x4 v4 = *reinterpret_cast<const f32x4*>(emb + (size_t)(i4 > 0 ? i4 - 1 : 0) * EMB + le);
      s += v0 * (i0 > 0 ? 1.f : 0.f) + v1 * (i1 > 0 ? 1.f : 0.f) + v2 * (i2 > 0 ? 1.f : 0.f) +
           v3 * (i3 > 0 ? 1.f : 0.f) + v4 * (i4 > 0 ? 1.f : 0.f);
    }
    float inv = 1.0f / slen[b];
    s *= inv;
    *reinterpret_cast<f32x4*>(accf + (size_t)b * EMB + le) = s;
    *reinterpret_cast<ushort4*>(xb + (size_t)b * EMB + le) = f2bf4(s);
  }
}

// ---- GEMM 128x128, BK=64, XOR-swizzled LDS, split-K via blockIdx.z (r8/r13-proven) ----
// C[M][N] = sum_k Am[m][k]*Bt[n][k]. LDS[r][c] = global[r][c^(r&7)] (16B chunks).
template <typename OUT_T>
__global__ __launch_bounds__(256, 3) void gemm_bt(const u16* __restrict__ Am,
                                                  const u16* __restrict__ Bt,
                                                  OUT_T* __restrict__ C,
                                                  int M, int N, int K, size_t zstride) {
  __shared__ __align__(16) u16 As[128 * 64];
  __shared__ __align__(16) u16 Bs[128 * 64];
  const int tid = threadIdx.x;
  const int lane = tid & 63;
  const int wid = tid >> 6;
  const int wr = wid >> 1, wc = wid & 1;  // 2x2 waves, 64x64 each
  const int row0 = blockIdx.y * 128, col0 = blockIdx.x * 128;
  const int kslice = K / (int)gridDim.z;
  const int kb = blockIdx.z * kslice, ke = kb + kslice;
  C += (size_t)blockIdx.z * zstride;

  f32x4 acc[4][4];
#pragma unroll
  for (int m = 0; m < 4; m++)
#pragma unroll
    for (int n = 0; n < 4; n++)
#pragma unroll
      for (int j = 0; j < 4; j++) acc[m][n][j] = 0.0f;

  const int lrow = lane & 15;
  const int lhi = lane >> 4;
  const int sw7 = lane & 7;                         // == frag row & 7
  const int cswz = ((lane & 7) ^ (lane >> 3)) * 8;  // inverse-swizzled source k-offset
  const int srow = wid * 8 + (lane >> 3);

  for (int k0 = kb; k0 < ke; k0 += 64) {
#pragma unroll
    for (int i = 0; i < 4; i++) {
      int r = i * 32 + srow;
      __builtin_amdgcn_global_load_lds(
          (const __attribute__((address_space(1))) void*)(Am + (size_t)(row0 + r) * K + k0 + cswz),
          (__attribute__((address_space(3))) void*)(As + (size_t)(i * 256 + wid * 64) * 8),
          16, 0, 0);
      __builtin_amdgcn_global_load_lds(
          (const __attribute__((address_space(1))) void*)(Bt + (size_t)(col0 + r) * K + k0 + cswz),
          (__attribute__((address_space(3))) void*)(Bs + (size_t)(i * 256 + wid * 64) * 8),
          16, 0, 0);
    }
    __syncthreads();

#pragma unroll
    for (int kk = 0; kk < 2; kk++) {
      const int co = ((kk * 4 + lhi) ^ sw7) * 8;
      bf16x8 af[4], bfv[4];
#pragma unroll
      for (int m = 0; m < 4; m++)
        af[m] = *reinterpret_cast<const bf16x8*>(As + (size_t)(wr * 64 + m * 16 + lrow) * 64 + co);
#pragma unroll
      for (int n = 0; n < 4; n++)
        bfv[n] = *reinterpret_cast<const bf16x8*>(Bs + (size_t)(wc * 64 + n * 16 + lrow) * 64 + co);
#pragma unroll
      for (int m = 0; m < 4; m++)
#pragma unroll
        for (int n = 0; n < 4; n++)
          acc[m][n] = __builtin_amdgcn_mfma_f32_16x16x32_bf16(af[m], bfv[n], acc[m][n], 0, 0, 0);
    }
    __syncthreads();
  }

#pragma unroll
  for (int m = 0; m < 4; m++) {
#pragma unroll
    for (int j = 0; j < 4; j++) {
      int r = row0 + wr * 64 + m * 16 + lhi * 4 + j;
      OUT_T* cp = C + (size_t)r * N + col0 + wc * 64 + lrow;
#pragma unroll
      for (int n = 0; n < 4; n++) cp[n * 16] = cvt_out<OUT_T>(acc[m][n][j]);
    }
  }
}

// ---- GEMM 64x64, K=256 staged in ONE shot (single barrier): yT = W x^T (r9-13 proven) ----
__global__ __launch_bounds__(256) void gemm64_ss(const u16* __restrict__ Am,
                                                 const u16* __restrict__ Bt,
                                                 u16* __restrict__ C, int N) {
  __shared__ __align__(16) u16 As[64 * 256];
  __shared__ __align__(16) u16 Bs[64 * 256];
  const int tid = threadIdx.x;
  const int lane = tid & 63;
  const int wid = tid >> 6;
  const int wr = wid >> 1, wc = wid & 1;
  const int row0 = blockIdx.y * 64, col0 = blockIdx.x * 64;
  const int lrow = lane & 15;
  const int lhi = lane >> 4;
  const int sw7 = lane & 7;

#pragma unroll
  for (int i = 0; i < 8; i++) {
    int row = i * 8 + (tid >> 5);
    int sc = (tid & 31) ^ (row & 7);
    __builtin_amdgcn_global_load_lds(
        (const __attribute__((address_space(1))) void*)(Am + (size_t)(row0 + row) * EMB + sc * 8),
        (__attribute__((address_space(3))) void*)((char*)As + (i * 256 + wid * 64) * 16), 16, 0, 0);
    __builtin_amdgcn_global_load_lds(
        (const __attribute__((address_space(1))) void*)(Bt + (size_t)(col0 + row) * EMB + sc * 8),
        (__attribute__((address_space(3))) void*)((char*)Bs + (i * 256 + wid * 64) * 16), 16, 0, 0);
  }
  __syncthreads();

  f32x4 acc[2][2];
#pragma unroll
  for (int m = 0; m < 2; m++)
#pragma unroll
    for (int n = 0; n < 2; n++)
#pragma unroll
      for (int j = 0; j < 4; j++) acc[m][n][j] = 0.0f;

#pragma unroll
  for (int ks = 0; ks < 8; ks++) {
    const int co = ((ks * 4 + lhi) ^ sw7) * 8;
    bf16x8 af[2], bfv[2];
#pragma unroll
    for (int m = 0; m < 2; m++)
      af[m] = *reinterpret_cast<const bf16x8*>(As + (size_t)(wr * 32 + m * 16 + lrow) * 256 + co);
#pragma unroll
    for (int n = 0; n < 2; n++)
      bfv[n] = *reinterpret_cast<const bf16x8*>(Bs + (size_t)(wc * 32 + n * 16 + lrow) * 256 + co);
#pragma unroll
    for (int m = 0; m < 2; m++)
#pragma unroll
      for (int n = 0; n < 2; n++)
        acc[m][n] = __builtin_amdgcn_mfma_f32_16x16x32_bf16(af[m], bfv[n], acc[m][n], 0, 0, 0);
  }

#pragma unroll
  for (int m = 0; m < 2; m++) {
#pragma unroll
    for (int j = 0; j < 4; j++) {
      int r = row0 + wr * 32 + m * 16 + lhi * 4 + j;
      u16* cp = C + (size_t)r * N + col0 + wc * 32 + lrow;
#pragma unroll
      for (int n = 0; n < 2; n++) cp[n * 16] = f2bf(acc[m][n][j]);
    }
  }
}

// ---- sum bf16 split-K partials -> bf16 (for uT); SPLITK unrolled ----
__global__ void uredux(const u16* __restrict__ zp, u16* __restrict__ uT,
                       int n4, size_t zstride4) {
  int i = blockIdx.x * blockDim.x + threadIdx.x;
  if (i < n4) {
    ushort4 v[SPLITK];
#pragma unroll
    for (int k = 0; k < SPLITK; k++)
      v[k] = reinterpret_cast<const ushort4*>(zp)[(size_t)k * zstride4 + i];
    f32x4 s = {0.f, 0.f, 0.f, 0.f};
#pragma unroll
    for (int k = 0; k < SPLITK; k++) s += bfu4(v[k]);
    reinterpret_cast<ushort4*>(uT)[i] = f2bf4(s);
  }
}

// ---- bf16 split-K reduce + row norm + accumulate (+final scale); SPLITK unrolled ----
__global__ void norm_acc(const u16* __restrict__ zp, size_t zstride,
                         float* __restrict__ acc, u16* __restrict__ xb,
                         float* __restrict__ outp, int fin) {
  int b = blockIdx.x, t = threadIdx.x;
  size_t i = (size_t)b * EMB + t;
  u16 h[SPLITK];
#pragma unroll
  for (int s = 0; s < SPLITK; s++) h[s] = zp[(size_t)s * zstride + i];
  float v = 0.0f;
#pragma unroll
  for (int s = 0; s < SPLITK; s++) v += bf2f(h[s]);
  float s2 = v * v;
#pragma unroll
  for (int o = 32; o > 0; o >>= 1) s2 += __shfl_down(s2, o, 64);
  __shared__ float ws4[4];
  if ((t & 63) == 0) ws4[t >> 6] = s2;
  __syncthreads();
  float tot = ws4[0] + ws4[1] + ws4[2] + ws4[3];
  float rn = 1.0f / fmaxf(sqrtf(tot), 1e-12f);
  if (fin) {
    outp[i] = (acc[i] + v * rn) * 0.25f;
  } else {
    acc[i] += v * rn;
    xb[i] = f2bf(v);
  }
}

// ---- launch ----
// pack(D,A,w) co-executes with gather (block-specialized, independent roles).
// Per layer: yT = Wx^T (gemm64_ss) ; uT = (A@y)^T (gemm_bt splitK=8 -> uredux) ;
// z = D@u (gemm_bt splitK=8 -> norm_acc).
extern "C" void kernel_launch(void* const* d_in, const int* in_sizes, int n_in,
                              void* d_out, int out_size, void* d_ws, size_t ws_size,
                              hipStream_t stream) {
  const float* emb   = (const float*)d_in[0];
  const float* D     = (const float*)d_in[1];
  const float* A     = (const float*)d_in[2];
  const int*   items = (const int*)d_in[3];
  const float* slen  = (const float*)d_in[4];
  const float* w     = (const float*)d_in[5];
  float* out = (float*)d_out;

  // workspace carve (~90.4 MB)
  char* p = (char*)d_ws;
  u16* Db   = (u16*)p;   p += (size_t)NB * NB * 2;             // 32 MB
  u16* Ab   = (u16*)p;   p += (size_t)NB * NB * 2;             // 32 MB
  u16* zp   = (u16*)p;   p += (size_t)SPLITK * NB * EMB * 2;   // 16 MB
  float* accf = (float*)p; p += (size_t)NB * EMB * 4;          // 4 MB
  u16* xb   = (u16*)p;   p += (size_t)NB * EMB * 2;            // 2 MB
  u16* yT   = (u16*)p;   p += (size_t)EMB * NB * 2;            // 2 MB
  u16* uT   = (u16*)p;   p += (size_t)EMB * NB * 2;            // 2 MB
  u16* wb   = (u16*)p;   p += (size_t)LAYERS * EMB * EMB * 2;  // 0.4 MB

  pack_gather<<<PACK_BLOCKS + NB / 4, 256, 0, stream>>>(D, A, w, emb, items, slen,
                                                        Db, Ab, wb, accf, xb);

  for (int i = 0; i < LAYERS; i++) {
    // yT[e][b] = sum_f W[e][f] * x[b][f]
    gemm64_ss<<<dim3(NB / 64, EMB / 64), 256, 0, stream>>>(wb + (size_t)i * EMB * EMB, xb, yT,
                                                           NB);
    // uT partials: zp[s][e][b] = partial_j yT[e][j] * Ab[b][j]  (splitK=8)
    gemm_bt<u16><<<dim3(NB / 128, EMB / 128, SPLITK), 256, 0, stream>>>(
        yT, Ab, zp, EMB, NB, NB, (size_t)EMB * NB);
    uredux<<<EMB * NB / 4 / 256, 256, 0, stream>>>(zp, uT, EMB * NB / 4,
                                                   (size_t)EMB * NB / 4);
    // z partials: zp[s][b][e] = partial_j Db[b][j] * uT[e][j]   (splitK=8)
    gemm_bt<u16><<<dim3(EMB / 128, NB / 128, SPLITK), 256, 0, stream>>>(
        Db, uT, zp, NB, EMB, NB, (size_t)NB * EMB);
    norm_acc<<<NB, 256, 0, stream>>>(zp, (size_t)NB * EMB, accf, xb, out, i == LAYERS - 1);
  }
}

// Round 16
// 199.165 us; speedup vs baseline: 1.1024x; 1.0288x over previous
//
#include <hip/hip_runtime.h>
#include <hip/hip_bf16.h>
#include <cstdint>
#include <cstddef>

#define LAYERS 3
#define EMB 256
#define NB 4096
#define MAXLEN 50
#define NITEMS 50000
#define SPLITK 8

typedef float f32x4 __attribute__((ext_vector_type(4)));
typedef __bf16 bf16x8 __attribute__((ext_vector_type(8)));
typedef unsigned short u16;

static __device__ __forceinline__ u16 f2bf(float f) {
  union { float f; uint32_t u; } v; v.f = f;
  uint32_t r = v.u + 0x7FFFu + ((v.u >> 16) & 1u);
  return (u16)(r >> 16);
}

static __device__ __forceinline__ float bf2f(u16 h) {
  union { uint32_t u; float f; } v; v.u = (uint32_t)h << 16; return v.f;
}

static __device__ __forceinline__ f32x4 bfu4(ushort4 h) {
  f32x4 r; r.x = bf2f(h.x); r.y = bf2f(h.y); r.z = bf2f(h.z); r.w = bf2f(h.w);
  return r;
}

static __device__ __forceinline__ ushort4 f2bf4(f32x4 v) {
  ushort4 o; o.x = f2bf(v.x); o.y = f2bf(v.y); o.z = f2bf(v.z); o.w = f2bf(v.w);
  return o;
}

template <typename T> __device__ __forceinline__ T cvt_out(float v);
template <> __device__ __forceinline__ float cvt_out<float>(float v) { return v; }
template <> __device__ __forceinline__ u16 cvt_out<u16>(float v) { return f2bf(v); }

#define N4_D (NB * NB / 4)
#define N4_W (LAYERS * EMB * EMB / 4)
#define N4_E ((NITEMS + 1) * EMB / 4)

// ---- single grid-stride pack: D, A, w -> bf16; emb -> padded bf16 table (r8-proven) ----
__global__ void pack_all(const float* __restrict__ D, const float* __restrict__ A,
                         const float* __restrict__ w, const float* __restrict__ emb,
                         u16* __restrict__ Db, u16* __restrict__ Ab,
                         u16* __restrict__ wb, u16* __restrict__ ebp) {
  const int total = N4_D + N4_D + N4_W + N4_E;
  for (int i = blockIdx.x * blockDim.x + threadIdx.x; i < total;
       i += gridDim.x * blockDim.x) {
    int j = i;
    if (j < N4_D) {
      reinterpret_cast<ushort4*>(Db)[j] = f2bf4(reinterpret_cast<const f32x4*>(D)[j]);
    } else if ((j -= N4_D) < N4_D) {
      reinterpret_cast<ushort4*>(Ab)[j] = f2bf4(reinterpret_cast<const f32x4*>(A)[j]);
    } else if ((j -= N4_D) < N4_W) {
      reinterpret_cast<ushort4*>(wb)[j] = f2bf4(reinterpret_cast<const f32x4*>(w)[j]);
    } else {
      j -= N4_W;
      ushort4 o = {0, 0, 0, 0};
      if (j >= EMB / 4) o = f2bf4(reinterpret_cast<const f32x4*>(emb)[j - EMB / 4]);
      reinterpret_cast<ushort4*>(ebp)[j] = o;
    }
  }
}

// ---- gather + mean pool (1 wave/session, bf16 padded table, 5-deep MLP; r8-proven) ----
__global__ void gather_mean(const u16* __restrict__ ebp, const int* __restrict__ items,
                            const float* __restrict__ slen, float* __restrict__ acc,
                            u16* __restrict__ xb) {
  int w = threadIdx.x >> 6, lane = threadIdx.x & 63;
  int b = blockIdx.x * 4 + w;
  f32x4 s = {0.f, 0.f, 0.f, 0.f};
  const int* it = items + (size_t)b * MAXLEN;
  const int le = lane * 4;
#pragma unroll 2
  for (int l = 0; l < MAXLEN; l += 5) {
    int i0 = it[l], i1 = it[l + 1], i2 = it[l + 2], i3 = it[l + 3], i4 = it[l + 4];
    ushort4 v0 = *reinterpret_cast<const ushort4*>(ebp + (size_t)i0 * EMB + le);
    ushort4 v1 = *reinterpret_cast<const ushort4*>(ebp + (size_t)i1 * EMB + le);
    ushort4 v2 = *reinterpret_cast<const ushort4*>(ebp + (size_t)i2 * EMB + le);
    ushort4 v3 = *reinterpret_cast<const ushort4*>(ebp + (size_t)i3 * EMB + le);
    ushort4 v4 = *reinterpret_cast<const ushort4*>(ebp + (size_t)i4 * EMB + le);
    s += bfu4(v0) + bfu4(v1) + bfu4(v2) + bfu4(v3) + bfu4(v4);
  }
  float inv = 1.0f / slen[b];
  s *= inv;
  *reinterpret_cast<f32x4*>(acc + (size_t)b * EMB + le) = s;
  *reinterpret_cast<ushort4*>(xb + (size_t)b * EMB + le) = f2bf4(s);
}

// ---- GEMM 128x128, BK=64, XOR-swizzled LDS, split-K via blockIdx.z (r8/r13-proven) ----
// C[M][N] = sum_k Am[m][k]*Bt[n][k]. LDS[r][c] = global[r][c^(r&7)] (16B chunks).
template <typename OUT_T>
__global__ __launch_bounds__(256, 3) void gemm_bt(const u16* __restrict__ Am,
                                                  const u16* __restrict__ Bt,
                                                  OUT_T* __restrict__ C,
                                                  int M, int N, int K, size_t zstride) {
  __shared__ __align__(16) u16 As[128 * 64];
  __shared__ __align__(16) u16 Bs[128 * 64];
  const int tid = threadIdx.x;
  const int lane = tid & 63;
  const int wid = tid >> 6;
  const int wr = wid >> 1, wc = wid & 1;  // 2x2 waves, 64x64 each
  const int row0 = blockIdx.y * 128, col0 = blockIdx.x * 128;
  const int kslice = K / (int)gridDim.z;
  const int kb = blockIdx.z * kslice, ke = kb + kslice;
  C += (size_t)blockIdx.z * zstride;

  f32x4 acc[4][4];
#pragma unroll
  for (int m = 0; m < 4; m++)
#pragma unroll
    for (int n = 0; n < 4; n++)
#pragma unroll
      for (int j = 0; j < 4; j++) acc[m][n][j] = 0.0f;

  const int lrow = lane & 15;
  const int lhi = lane >> 4;
  const int sw7 = lane & 7;                         // == frag row & 7
  const int cswz = ((lane & 7) ^ (lane >> 3)) * 8;  // inverse-swizzled source k-offset
  const int srow = wid * 8 + (lane >> 3);

  for (int k0 = kb; k0 < ke; k0 += 64) {
#pragma unroll
    for (int i = 0; i < 4; i++) {
      int r = i * 32 + srow;
      __builtin_amdgcn_global_load_lds(
          (const __attribute__((address_space(1))) void*)(Am + (size_t)(row0 + r) * K + k0 + cswz),
          (__attribute__((address_space(3))) void*)(As + (size_t)(i * 256 + wid * 64) * 8),
          16, 0, 0);
      __builtin_amdgcn_global_load_lds(
          (const __attribute__((address_space(1))) void*)(Bt + (size_t)(col0 + r) * K + k0 + cswz),
          (__attribute__((address_space(3))) void*)(Bs + (size_t)(i * 256 + wid * 64) * 8),
          16, 0, 0);
    }
    __syncthreads();

#pragma unroll
    for (int kk = 0; kk < 2; kk++) {
      const int co = ((kk * 4 + lhi) ^ sw7) * 8;
      bf16x8 af[4], bfv[4];
#pragma unroll
      for (int m = 0; m < 4; m++)
        af[m] = *reinterpret_cast<const bf16x8*>(As + (size_t)(wr * 64 + m * 16 + lrow) * 64 + co);
#pragma unroll
      for (int n = 0; n < 4; n++)
        bfv[n] = *reinterpret_cast<const bf16x8*>(Bs + (size_t)(wc * 64 + n * 16 + lrow) * 64 + co);
#pragma unroll
      for (int m = 0; m < 4; m++)
#pragma unroll
        for (int n = 0; n < 4; n++)
          acc[m][n] = __builtin_amdgcn_mfma_f32_16x16x32_bf16(af[m], bfv[n], acc[m][n], 0, 0, 0);
    }
    __syncthreads();
  }

#pragma unroll
  for (int m = 0; m < 4; m++) {
#pragma unroll
    for (int j = 0; j < 4; j++) {
      int r = row0 + wr * 64 + m * 16 + lhi * 4 + j;
      OUT_T* cp = C + (size_t)r * N + col0 + wc * 64 + lrow;
#pragma unroll
      for (int n = 0; n < 4; n++) cp[n * 16] = cvt_out<OUT_T>(acc[m][n][j]);
    }
  }
}

// ---- GEMM 64x64, K=256 staged in ONE shot (single barrier): yT = W x^T (r9-13 proven) ----
__global__ __launch_bounds__(256) void gemm64_ss(const u16* __restrict__ Am,
                                                 const u16* __restrict__ Bt,
                                                 u16* __restrict__ C, int N) {
  __shared__ __align__(16) u16 As[64 * 256];
  __shared__ __align__(16) u16 Bs[64 * 256];
  const int tid = threadIdx.x;
  const int lane = tid & 63;
  const int wid = tid >> 6;
  const int wr = wid >> 1, wc = wid & 1;
  const int row0 = blockIdx.y * 64, col0 = blockIdx.x * 64;
  const int lrow = lane & 15;
  const int lhi = lane >> 4;
  const int sw7 = lane & 7;

#pragma unroll
  for (int i = 0; i < 8; i++) {
    int row = i * 8 + (tid >> 5);
    int sc = (tid & 31) ^ (row & 7);
    __builtin_amdgcn_global_load_lds(
        (const __attribute__((address_space(1))) void*)(Am + (size_t)(row0 + row) * EMB + sc * 8),
        (__attribute__((address_space(3))) void*)((char*)As + (i * 256 + wid * 64) * 16), 16, 0, 0);
    __builtin_amdgcn_global_load_lds(
        (const __attribute__((address_space(1))) void*)(Bt + (size_t)(col0 + row) * EMB + sc * 8),
        (__attribute__((address_space(3))) void*)((char*)Bs + (i * 256 + wid * 64) * 16), 16, 0, 0);
  }
  __syncthreads();

  f32x4 acc[2][2];
#pragma unroll
  for (int m = 0; m < 2; m++)
#pragma unroll
    for (int n = 0; n < 2; n++)
#pragma unroll
      for (int j = 0; j < 4; j++) acc[m][n][j] = 0.0f;

#pragma unroll
  for (int ks = 0; ks < 8; ks++) {
    const int co = ((ks * 4 + lhi) ^ sw7) * 8;
    bf16x8 af[2], bfv[2];
#pragma unroll
    for (int m = 0; m < 2; m++)
      af[m] = *reinterpret_cast<const bf16x8*>(As + (size_t)(wr * 32 + m * 16 + lrow) * 256 + co);
#pragma unroll
    for (int n = 0; n < 2; n++)
      bfv[n] = *reinterpret_cast<const bf16x8*>(Bs + (size_t)(wc * 32 + n * 16 + lrow) * 256 + co);
#pragma unroll
    for (int m = 0; m < 2; m++)
#pragma unroll
      for (int n = 0; n < 2; n++)
        acc[m][n] = __builtin_amdgcn_mfma_f32_16x16x32_bf16(af[m], bfv[n], acc[m][n], 0, 0, 0);
  }

#pragma unroll
  for (int m = 0; m < 2; m++) {
#pragma unroll
    for (int j = 0; j < 4; j++) {
      int r = row0 + wr * 32 + m * 16 + lhi * 4 + j;
      u16* cp = C + (size_t)r * N + col0 + wc * 32 + lrow;
#pragma unroll
      for (int n = 0; n < 2; n++) cp[n * 16] = f2bf(acc[m][n][j]);
    }
  }
}

// ---- sum bf16 split-K partials -> bf16 (for uT); SPLITK unrolled, 8 loads in flight ----
__global__ void uredux(const u16* __restrict__ zp, u16* __restrict__ uT,
                       int n4, size_t zstride4) {
  int i = blockIdx.x * blockDim.x + threadIdx.x;
  if (i < n4) {
    ushort4 v[SPLITK];
#pragma unroll
    for (int k = 0; k < SPLITK; k++)
      v[k] = reinterpret_cast<const ushort4*>(zp)[(size_t)k * zstride4 + i];
    f32x4 s = {0.f, 0.f, 0.f, 0.f};
#pragma unroll
    for (int k = 0; k < SPLITK; k++) s += bfu4(v[k]);
    reinterpret_cast<ushort4*>(uT)[i] = f2bf4(s);
  }
}

// ---- bf16 split-K reduce + row norm + accumulate (+final scale); SPLITK unrolled ----
__global__ void norm_acc(const u16* __restrict__ zp, size_t zstride,
                         float* __restrict__ acc, u16* __restrict__ xb,
                         float* __restrict__ outp, int fin) {
  int b = blockIdx.x, t = threadIdx.x;
  size_t i = (size_t)b * EMB + t;
  u16 h[SPLITK];
#pragma unroll
  for (int s = 0; s < SPLITK; s++) h[s] = zp[(size_t)s * zstride + i];
  float v = 0.0f;
#pragma unroll
  for (int s = 0; s < SPLITK; s++) v += bf2f(h[s]);
  float s2 = v * v;
#pragma unroll
  for (int o = 32; o > 0; o >>= 1) s2 += __shfl_down(s2, o, 64);
  __shared__ float ws4[4];
  if ((t & 63) == 0) ws4[t >> 6] = s2;
  __syncthreads();
  float tot = ws4[0] + ws4[1] + ws4[2] + ws4[3];
  float rn = 1.0f / fmaxf(sqrtf(tot), 1e-12f);
  if (fin) {
    outp[i] = (acc[i] + v * rn) * 0.25f;
  } else {
    acc[i] += v * rn;
    xb[i] = f2bf(v);
  }
}

// ---- launch ----
// Per layer: yT = Wx^T (gemm64_ss, single barrier) ; uT = (A@y)^T (gemm_bt splitK=8 ->
// uredux) ; z = D@u (gemm_bt splitK=8 -> norm_acc).  [r13 configuration — best measured]
extern "C" void kernel_launch(void* const* d_in, const int* in_sizes, int n_in,
                              void* d_out, int out_size, void* d_ws, size_t ws_size,
                              hipStream_t stream) {
  const float* emb   = (const float*)d_in[0];
  const float* D     = (const float*)d_in[1];
  const float* A     = (const float*)d_in[2];
  const int*   items = (const int*)d_in[3];
  const float* slen  = (const float*)d_in[4];
  const float* w     = (const float*)d_in[5];
  float* out = (float*)d_out;

  // workspace carve (~100 MB); zp (16 MB) overlays ebp (dead after gather_mean)
  char* p = (char*)d_ws;
  u16* Db   = (u16*)p;   p += (size_t)NB * NB * 2;             // 32 MB
  u16* Ab   = (u16*)p;   p += (size_t)NB * NB * 2;             // 32 MB
  float* accf = (float*)p; p += (size_t)NB * EMB * 4;          // 4 MB
  u16* xb   = (u16*)p;   p += (size_t)NB * EMB * 2;            // 2 MB
  u16* yT   = (u16*)p;   p += (size_t)EMB * NB * 2;            // 2 MB
  u16* uT   = (u16*)p;   p += (size_t)EMB * NB * 2;            // 2 MB
  u16* wb   = (u16*)p;   p += (size_t)LAYERS * EMB * EMB * 2;  // 0.4 MB
  u16* ebp  = (u16*)p;   p += (size_t)(NITEMS + 1) * EMB * 2;  // 25.6 MB
  u16* zp   = ebp;  // SPLITK x [NB][EMB] bf16 = 16 MB in dead ebp region

  pack_all<<<2048, 256, 0, stream>>>(D, A, w, emb, Db, Ab, wb, ebp);
  gather_mean<<<NB / 4, 256, 0, stream>>>(ebp, items, slen, accf, xb);

  for (int i = 0; i < LAYERS; i++) {
    // yT[e][b] = sum_f W[e][f] * x[b][f]
    gemm64_ss<<<dim3(NB / 64, EMB / 64), 256, 0, stream>>>(wb + (size_t)i * EMB * EMB, xb, yT,
                                                           NB);
    // uT partials: zp[s][e][b] = partial_j yT[e][j] * Ab[b][j]  (splitK=8)
    gemm_bt<u16><<<dim3(NB / 128, EMB / 128, SPLITK), 256, 0, stream>>>(
        yT, Ab, zp, EMB, NB, NB, (size_t)EMB * NB);
    uredux<<<EMB * NB / 4 / 256, 256, 0, stream>>>(zp, uT, EMB * NB / 4,
                                                   (size_t)EMB * NB / 4);
    // z partials: zp[s][b][e] = partial_j Db[b][j] * uT[e][j]   (splitK=8)
    gemm_bt<u16><<<dim3(EMB / 128, NB / 128, SPLITK), 256, 0, stream>>>(
        Db, uT, zp, NB, EMB, NB, (size_t)NB * EMB);
    norm_acc<<<NB, 256, 0, stream>>>(zp, (size_t)NB * EMB, accf, xb, out, i == LAYERS - 1);
  }
}